// Round 1
// baseline (166.730 us; speedup 1.0000x reference)
//
#include <hip/hip_runtime.h>

// RetinaNet target encoder for MI355X.
// Inputs: bboxes [N,4] f32 xyxy, labels [N] i32, priors [M,4] f32 cxcywh.
// Outputs (concat): reg_targets [M,4] f32, cls_targets [M] (written as f32).

static constexpr float NEG_THRESH = 0.4f;
static constexpr float POS_THRESH = 0.5f;
static constexpr int MAX_GT = 1024;

// Exact-op-order IoU matching the numpy reference; fp contraction off so
// results are bit-identical to numpy f32 (argmax stability).
__device__ __forceinline__ float iou_ab(float ax1, float ay1, float ax2, float ay2,
                                        float area_a,
                                        float bx1, float by1, float bx2, float by2,
                                        float area_b) {
#pragma clang fp contract(off)
    float ltx = fmaxf(ax1, bx1);
    float lty = fmaxf(ay1, by1);
    float rbx = fminf(ax2, bx2);
    float rby = fminf(ay2, by2);
    float w = rbx - ltx; if (w < 0.0f) w = 0.0f;
    float h = rby - lty; if (h < 0.0f) h = 0.0f;
    float inter = w * h;
    return inter / (area_a + area_b - inter);
}

// Kernel 1: per-prior max IoU + argmax over GTs (first-max wins, like np.argmax).
__global__ void per_prior_kernel(const float* __restrict__ bboxes,
                                 const float* __restrict__ priors,
                                 int* __restrict__ match_id,
                                 float* __restrict__ max_iou,
                                 int N, int M) {
#pragma clang fp contract(off)
    __shared__ float sx1[MAX_GT], sy1[MAX_GT], sx2[MAX_GT], sy2[MAX_GT], sar[MAX_GT];
    int tid = threadIdx.x;
    for (int i = tid; i < N; i += blockDim.x) {
        float4 g = reinterpret_cast<const float4*>(bboxes)[i];
        sx1[i] = g.x; sy1[i] = g.y; sx2[i] = g.z; sy2[i] = g.w;
        sar[i] = (g.z - g.x) * (g.w - g.y);
    }
    __syncthreads();

    int m = blockIdx.x * blockDim.x + tid;
    if (m >= M) return;

    float4 p = reinterpret_cast<const float4*>(priors)[m];
    // cxcywh -> xyxy exactly as reference
    float bx1 = p.x - p.z / 2.0f;
    float by1 = p.y - p.w / 2.0f;
    float bx2 = p.x + p.z / 2.0f;
    float by2 = p.y + p.w / 2.0f;
    float area_b = (bx2 - bx1) * (by2 - by1);

    float best = -1.0f;
    int bestn = 0;
    for (int n = 0; n < N; ++n) {
        float iou = iou_ab(sx1[n], sy1[n], sx2[n], sy2[n], sar[n],
                           bx1, by1, bx2, by2, area_b);
        if (iou > best) { best = iou; bestn = n; }  // strict > => first max
    }
    match_id[m] = bestn;
    max_iou[m] = best;
}

// Kernel 2: per-GT argmax over priors (first-max = smallest m among maxima).
__global__ void per_gt_kernel(const float* __restrict__ bboxes,
                              const float* __restrict__ priors,
                              int* __restrict__ force_prior,
                              int N, int M) {
#pragma clang fp contract(off)
    int n = blockIdx.x;
    int tid = threadIdx.x;
    float4 g = reinterpret_cast<const float4*>(bboxes)[n];
    float ax1 = g.x, ay1 = g.y, ax2 = g.z, ay2 = g.w;
    float area_a = (ax2 - ax1) * (ay2 - ay1);

    unsigned long long best = 0ULL;  // (iou_bits << 32) | (0xFFFFFFFF - m)
    for (int m = tid; m < M; m += blockDim.x) {
        float4 p = reinterpret_cast<const float4*>(priors)[m];
        float bx1 = p.x - p.z / 2.0f;
        float by1 = p.y - p.w / 2.0f;
        float bx2 = p.x + p.z / 2.0f;
        float by2 = p.y + p.w / 2.0f;
        float area_b = (bx2 - bx1) * (by2 - by1);
        float iou = iou_ab(ax1, ay1, ax2, ay2, area_a, bx1, by1, bx2, by2, area_b);
        unsigned long long packed =
            ((unsigned long long)__float_as_uint(iou) << 32) |
            (unsigned long long)(0xFFFFFFFFu - (unsigned)m);
        if (packed > best) best = packed;
    }

    __shared__ unsigned long long sred[256];
    sred[tid] = best;
    __syncthreads();
    for (int s = blockDim.x / 2; s > 0; s >>= 1) {
        if (tid < s) {
            unsigned long long o = sred[tid + s];
            if (o > sred[tid]) sred[tid] = o;
        }
        __syncthreads();
    }
    if (tid == 0) {
        unsigned low = (unsigned)(sred[0] & 0xFFFFFFFFull);
        force_prior[n] = (int)(0xFFFFFFFFu - low);
    }
}

// Kernel 3: forced assignment scatter, last n wins (numpy semantics) == max n.
__global__ void scatter_kernel(const int* __restrict__ force_prior,
                               int* __restrict__ force_n, int N) {
    int n = blockIdx.x * blockDim.x + threadIdx.x;
    if (n < N) atomicMax(&force_n[force_prior[n]], n);
}

// Kernel 4: encode reg + cls targets.
__global__ void encode_kernel(const float* __restrict__ bboxes,
                              const int* __restrict__ labels,
                              const float* __restrict__ priors,
                              const int* __restrict__ match_id,
                              const float* __restrict__ max_iou,
                              const int* __restrict__ force_n,
                              float* __restrict__ out, int M) {
#pragma clang fp contract(off)
    int m = blockIdx.x * blockDim.x + threadIdx.x;
    if (m >= M) return;

    int f = force_n[m];
    int mid;
    float iou;
    if (f >= 0) { mid = f; iou = POS_THRESH; }
    else        { mid = match_id[m]; iou = max_iou[m]; }

    float4 g = reinterpret_cast<const float4*>(bboxes)[mid];
    // xyxy -> cxcywh exactly as reference
    float mcx = (g.x + g.z) / 2.0f;
    float mcy = (g.y + g.w) / 2.0f;
    float mw = g.z - g.x;
    float mh = g.w - g.y;

    float4 p = reinterpret_cast<const float4*>(priors)[m];
    float dcx = ((mcx - p.x) / p.z) / 0.1f;
    float dcy = ((mcy - p.y) / p.w) / 0.1f;
    float dw = logf(mw / p.z) / 0.2f;
    float dh = logf(mh / p.w) / 0.2f;

    reinterpret_cast<float4*>(out)[m] = make_float4(dcx, dcy, dw, dh);

    int cls = labels[mid];
    if (iou < POS_THRESH) cls = -1;
    if (iou < NEG_THRESH) cls = 0;
    out[(size_t)4 * M + m] = (float)cls;
}

extern "C" void kernel_launch(void* const* d_in, const int* in_sizes, int n_in,
                              void* d_out, int out_size, void* d_ws, size_t ws_size,
                              hipStream_t stream) {
    const float* bboxes = (const float*)d_in[0];
    const int* labels = (const int*)d_in[1];
    const float* priors = (const float*)d_in[2];
    int N = in_sizes[1];
    int M = in_sizes[2] / 4;
    float* out = (float*)d_out;

    char* ws = (char*)d_ws;
    int* match_id = (int*)ws;                          // M ints
    float* max_iou = (float*)(ws + (size_t)M * 4);     // M floats
    int* force_n = (int*)(ws + (size_t)M * 8);         // M ints
    int* force_prior = (int*)(ws + (size_t)M * 12);    // N ints

    // force_n must be -1 each call (harness does not re-poison between replays)
    hipMemsetAsync(force_n, 0xFF, (size_t)M * 4, stream);

    per_prior_kernel<<<(M + 255) / 256, 256, 0, stream>>>(bboxes, priors, match_id, max_iou, N, M);
    per_gt_kernel<<<N, 256, 0, stream>>>(bboxes, priors, force_prior, N, M);
    scatter_kernel<<<(N + 255) / 256, 256, 0, stream>>>(force_prior, force_n, N);
    encode_kernel<<<(M + 255) / 256, 256, 0, stream>>>(bboxes, labels, priors,
                                                       match_id, max_iou, force_n, out, M);
}

// Round 2
// 101.710 us; speedup vs baseline: 1.6393x; 1.6393x over previous
//
#include <hip/hip_runtime.h>

// RetinaNet target encoder for MI355X — round 2: occupancy-split version.
// Inputs: bboxes [N,4] f32 xyxy, labels [N] i32, priors [M,4] f32 cxcywh.
// Outputs (concat): reg_targets [M,4] f32, cls_targets [M] (written as f32).
//
// N = 1024, M = 49104.
// Decomposition:
//   P : per-prior partial argmax over GT chunks (8 chunks of 128 GTs)
//       grid 192 x 8 = 1536 blocks  -> packed u64 partials [8][Mpad]
//   D : per-GT partial argmax over prior chunks (48 chunks of 1024 priors,
//       staged in LDS, 8 lanes per GT) -> packed u64 partials [N][48]
//   RS: reduce D partials per GT + atomicMax scatter (last-n-wins == max n)
//   E : reduce P partials per prior + encode reg/cls targets
// Packed u64 = (iou_bits << 32) | (0xFFFFFFFF - index): max() == (max iou,
// then smallest index) == numpy first-max argmax. Associative & commutative.

static constexpr float NEG_THRESH = 0.4f;
static constexpr float POS_THRESH = 0.5f;
static constexpr int N_GT = 1024;
static constexpr int GT_CHUNK = 128;   // GTs per P-block
static constexpr int NS = N_GT / GT_CHUNK;              // 8
static constexpr int P_CHUNK = 1024;   // priors per D-block
static constexpr int GT_GROUP = 32;    // GTs per D-block
static constexpr int MPAD = 49152;     // M rounded to 256

__device__ __forceinline__ float iou_ab(float ax1, float ay1, float ax2, float ay2,
                                        float area_a,
                                        float bx1, float by1, float bx2, float by2,
                                        float area_b) {
#pragma clang fp contract(off)
    float ltx = fmaxf(ax1, bx1);
    float lty = fmaxf(ay1, by1);
    float rbx = fminf(ax2, bx2);
    float rby = fminf(ay2, by2);
    float w = rbx - ltx; if (w < 0.0f) w = 0.0f;
    float h = rby - lty; if (h < 0.0f) h = 0.0f;
    float inter = w * h;
    return inter / (area_a + area_b - inter);
}

// ---------------- Kernel P: per-prior partial over one GT chunk ----------------
__global__ void __launch_bounds__(256) pp_partial_kernel(
        const float* __restrict__ bboxes,
        const float* __restrict__ priors,
        unsigned long long* __restrict__ part1,   // [NS][MPAD]
        int* __restrict__ force_n,                // [M], init to -1 here (ns==0)
        int M) {
#pragma clang fp contract(off)
    __shared__ float sx1[GT_CHUNK], sy1[GT_CHUNK], sx2[GT_CHUNK], sy2[GT_CHUNK], sar[GT_CHUNK];
    int tid = threadIdx.x;
    int ns = blockIdx.y;
    int n0 = ns * GT_CHUNK;
    if (tid < GT_CHUNK) {
        float4 g = reinterpret_cast<const float4*>(bboxes)[n0 + tid];
        sx1[tid] = g.x; sy1[tid] = g.y; sx2[tid] = g.z; sy2[tid] = g.w;
        sar[tid] = (g.z - g.x) * (g.w - g.y);
    }
    __syncthreads();

    int m = blockIdx.x * 256 + tid;
    if (m >= M) return;

    float4 p = reinterpret_cast<const float4*>(priors)[m];
    float bx1 = p.x - p.z / 2.0f;
    float by1 = p.y - p.w / 2.0f;
    float bx2 = p.x + p.z / 2.0f;
    float by2 = p.y + p.w / 2.0f;
    float area_b = (bx2 - bx1) * (by2 - by1);

    float best = -1.0f;
    int bestj = 0;
    for (int j = 0; j < GT_CHUNK; ++j) {
        float iou = iou_ab(sx1[j], sy1[j], sx2[j], sy2[j], sar[j],
                           bx1, by1, bx2, by2, area_b);
        if (iou > best) { best = iou; bestj = j; }   // strict > => first max
    }
    unsigned n_global = (unsigned)(n0 + bestj);
    part1[(size_t)ns * MPAD + m] =
        ((unsigned long long)__float_as_uint(best) << 32) |
        (unsigned long long)(0xFFFFFFFFu - n_global);

    if (ns == 0) force_n[m] = -1;   // init for RS's atomicMax (replay-safe)
}

// ---------------- Kernel D: per-GT partial over one prior chunk ----------------
__global__ void __launch_bounds__(256) pg_partial_kernel(
        const float* __restrict__ bboxes,
        const float* __restrict__ priors,
        unsigned long long* __restrict__ partD,   // [N_GT][gridDim.x]
        int M) {
#pragma clang fp contract(off)
    __shared__ float sx1[P_CHUNK], sy1[P_CHUNK], sx2[P_CHUNK], sy2[P_CHUNK], sar[P_CHUNK];
    int tid = threadIdx.x;
    int chunk = blockIdx.x;
    int nchunks = gridDim.x;
    int m0 = chunk * P_CHUNK;

    for (int i = tid; i < P_CHUNK; i += 256) {
        int m = m0 + i;
        if (m < M) {
            float4 p = reinterpret_cast<const float4*>(priors)[m];
            float bx1 = p.x - p.z / 2.0f;
            float by1 = p.y - p.w / 2.0f;
            float bx2 = p.x + p.z / 2.0f;
            float by2 = p.y + p.w / 2.0f;
            sx1[i] = bx1; sy1[i] = by1; sx2[i] = bx2; sy2[i] = by2;
            sar[i] = (bx2 - bx1) * (by2 - by1);
        }
    }
    __syncthreads();

    // 8 lanes per GT: thread t handles GT (t>>3), priors (t&7) + 8k.
    int g = blockIdx.y * GT_GROUP + (tid >> 3);
    int sub = tid & 7;
    float4 gb = reinterpret_cast<const float4*>(bboxes)[g];
    float ax1 = gb.x, ay1 = gb.y, ax2 = gb.z, ay2 = gb.w;
    float area_a = (ax2 - ax1) * (ay2 - ay1);

    unsigned long long best = 0ULL;
    for (int k = 0; k < P_CHUNK / 8; ++k) {
        int i = sub + 8 * k;
        int m = m0 + i;
        if (m < M) {
            float iou = iou_ab(ax1, ay1, ax2, ay2, area_a,
                               sx1[i], sy1[i], sx2[i], sy2[i], sar[i]);
            unsigned long long packed =
                ((unsigned long long)__float_as_uint(iou) << 32) |
                (unsigned long long)(0xFFFFFFFFu - (unsigned)m);
            if (packed > best) best = packed;
        }
    }
    // reduce across the 8 lanes of this GT (same wave, contiguous lanes)
    for (int mask = 1; mask < 8; mask <<= 1) {
        unsigned long long o = __shfl_xor(best, mask);
        if (o > best) best = o;
    }
    if (sub == 0) partD[(size_t)g * nchunks + chunk] = best;
}

// ---------------- Kernel RS: reduce per-GT partials + scatter ----------------
__global__ void reduce_scatter_kernel(const unsigned long long* __restrict__ partD,
                                      int* __restrict__ force_n,
                                      int nchunks) {
    int n = blockIdx.x * blockDim.x + threadIdx.x;
    if (n >= N_GT) return;
    unsigned long long best = 0ULL;
    for (int c = 0; c < nchunks; ++c) {
        unsigned long long v = partD[(size_t)n * nchunks + c];
        if (v > best) best = v;
    }
    int m = (int)(0xFFFFFFFFu - (unsigned)(best & 0xFFFFFFFFull));
    atomicMax(&force_n[m], n);   // duplicate priors: last write in np == max n
}

// ---------------- Kernel E: reduce per-prior partials + encode ----------------
__global__ void __launch_bounds__(256) encode_kernel(
        const float* __restrict__ bboxes,
        const int* __restrict__ labels,
        const float* __restrict__ priors,
        const unsigned long long* __restrict__ part1,  // [NS][MPAD]
        const int* __restrict__ force_n,
        float* __restrict__ out, int M) {
#pragma clang fp contract(off)
    int m = blockIdx.x * 256 + threadIdx.x;
    if (m >= M) return;

    unsigned long long best = part1[m];
    for (int ns = 1; ns < NS; ++ns) {
        unsigned long long v = part1[(size_t)ns * MPAD + m];
        if (v > best) best = v;
    }
    float iou = __uint_as_float((unsigned)(best >> 32));
    int mid = (int)(0xFFFFFFFFu - (unsigned)(best & 0xFFFFFFFFull));

    int f = force_n[m];
    if (f >= 0) { mid = f; iou = POS_THRESH; }

    float4 g = reinterpret_cast<const float4*>(bboxes)[mid];
    float mcx = (g.x + g.z) / 2.0f;
    float mcy = (g.y + g.w) / 2.0f;
    float mw = g.z - g.x;
    float mh = g.w - g.y;

    float4 p = reinterpret_cast<const float4*>(priors)[m];
    float dcx = ((mcx - p.x) / p.z) / 0.1f;
    float dcy = ((mcy - p.y) / p.w) / 0.1f;
    float dw = logf(mw / p.z) / 0.2f;
    float dh = logf(mh / p.w) / 0.2f;

    reinterpret_cast<float4*>(out)[m] = make_float4(dcx, dcy, dw, dh);

    int cls = labels[mid];
    if (iou < POS_THRESH) cls = -1;
    if (iou < NEG_THRESH) cls = 0;
    out[(size_t)4 * M + m] = (float)cls;
}

extern "C" void kernel_launch(void* const* d_in, const int* in_sizes, int n_in,
                              void* d_out, int out_size, void* d_ws, size_t ws_size,
                              hipStream_t stream) {
    const float* bboxes = (const float*)d_in[0];
    const int* labels = (const int*)d_in[1];
    const float* priors = (const float*)d_in[2];
    int M = in_sizes[2] / 4;
    float* out = (float*)d_out;

    int mb = (M + 255) / 256;                 // 192 prior blocks for P/E
    int nchunks = (M + P_CHUNK - 1) / P_CHUNK; // 48 prior chunks for D

    char* ws = (char*)d_ws;
    unsigned long long* part1 = (unsigned long long*)ws;                 // NS*MPAD u64 = 3.0 MB
    unsigned long long* partD = (unsigned long long*)(ws + (size_t)NS * MPAD * 8);  // N*nchunks u64
    int* force_n = (int*)(ws + (size_t)NS * MPAD * 8 + (size_t)N_GT * nchunks * 8); // M ints

    pp_partial_kernel<<<dim3(mb, NS), 256, 0, stream>>>(bboxes, priors, part1, force_n, M);
    pg_partial_kernel<<<dim3(nchunks, N_GT / GT_GROUP), 256, 0, stream>>>(bboxes, priors, partD, M);
    reduce_scatter_kernel<<<(N_GT + 255) / 256, 256, 0, stream>>>(partD, force_n, nchunks);
    encode_kernel<<<mb, 256, 0, stream>>>(bboxes, labels, priors, part1, force_n, out, M);
}

// Round 3
// 92.464 us; speedup vs baseline: 1.8032x; 1.1000x over previous
//
#include <hip/hip_runtime.h>

// RetinaNet target encoder for MI355X — round 3: fused single-pass IoU.
// Inputs: bboxes [N,4] f32 xyxy, labels [N] i32, priors [M,4] f32 cxcywh.
// Outputs (concat): reg_targets [M,4] f32, cls_targets [M] (written as f32).
//
// N = 1024, M = 49104.  Each IoU pair is computed exactly ONCE and feeds:
//   (a) per-prior argmax over GTs  — per-thread register tracking
//   (b) per-GT argmax over priors  — per-wave ballot reduce -> LDS -> global
//        packed u64 = (iou_bits<<32) | (0xFFFFFFFF - index): max() ==
//        (max iou, then smallest index) == numpy first-max argmax.
// Thread t owns prior m = blockIdx.x*256 + t, so within a wave lane order ==
// m order: lowest equal lane in the ballot == smallest m (numpy tie-break).

static constexpr float NEG_THRESH = 0.4f;
static constexpr float POS_THRESH = 0.5f;
static constexpr int N_GT = 1024;
static constexpr int GT_CHUNK = 128;
static constexpr int NS = N_GT / GT_CHUNK;   // 8 GT chunks
static constexpr int MPAD = 49152;           // M rounded up to 256

__device__ __forceinline__ float iou_ab(float ax1, float ay1, float ax2, float ay2,
                                        float area_a,
                                        float bx1, float by1, float bx2, float by2,
                                        float area_b) {
#pragma clang fp contract(off)
    float ltx = fmaxf(ax1, bx1);
    float lty = fmaxf(ay1, by1);
    float rbx = fminf(ax2, bx2);
    float rby = fminf(ay2, by2);
    float w = rbx - ltx; if (w < 0.0f) w = 0.0f;
    float h = rby - lty; if (h < 0.0f) h = 0.0f;
    float inter = w * h;
    return inter / (area_a + area_b - inter);
}

// ---------------- Fused kernel: one pass over all (prior, GT) pairs ----------
__global__ void __launch_bounds__(256) fused_kernel(
        const float* __restrict__ bboxes,
        const float* __restrict__ priors,
        unsigned long long* __restrict__ part1,   // [NS][MPAD] per-prior partials
        unsigned long long* __restrict__ partG,   // [N_GT] per-GT packed (atomicMax)
        int* __restrict__ force_n,                // [M] init -1 here (ns==0)
        int M) {
#pragma clang fp contract(off)
    __shared__ float4 sbox[GT_CHUNK];
    __shared__ float sar[GT_CHUNK];
    __shared__ unsigned long long swave[4][GT_CHUNK];  // per-wave per-GT packed

    int tid = threadIdx.x;
    int ns = blockIdx.y;
    int n0 = ns * GT_CHUNK;

    if (tid < GT_CHUNK) {
        float4 g = reinterpret_cast<const float4*>(bboxes)[n0 + tid];
        sbox[tid] = g;
        sar[tid] = (g.z - g.x) * (g.w - g.y);
    }
    __syncthreads();

    int m = blockIdx.x * 256 + tid;
    int lane = tid & 63;
    int wid = tid >> 6;
    int wm_base = m - lane;   // m of lane 0 of this wave

    // Prior box in registers (degenerate zero-box for tail threads: iou == 0).
    float bx1 = 0.0f, by1 = 0.0f, bx2 = 0.0f, by2 = 0.0f, area_b = 0.0f;
    if (m < M) {
        float4 p = reinterpret_cast<const float4*>(priors)[m];
        bx1 = p.x - p.z / 2.0f;
        by1 = p.y - p.w / 2.0f;
        bx2 = p.x + p.z / 2.0f;
        by2 = p.y + p.w / 2.0f;
        area_b = (bx2 - bx1) * (by2 - by1);
    }

    float best = -1.0f;
    int bestj = 0;
    for (int j = 0; j < GT_CHUNK; ++j) {
        float4 g = sbox[j];            // broadcast read (all lanes same addr)
        float ga = sar[j];
        float iou = iou_ab(g.x, g.y, g.z, g.w, ga, bx1, by1, bx2, by2, area_b);

        // (a) per-prior argmax: strict > with ascending j == numpy first-max
        if (iou > best) { best = iou; bestj = j; }

        // (b) per-GT max over this wave's 64 priors
        float wmax = iou;
        wmax = fmaxf(wmax, __shfl_xor(wmax, 1));
        wmax = fmaxf(wmax, __shfl_xor(wmax, 2));
        wmax = fmaxf(wmax, __shfl_xor(wmax, 4));
        wmax = fmaxf(wmax, __shfl_xor(wmax, 8));
        wmax = fmaxf(wmax, __shfl_xor(wmax, 16));
        wmax = fmaxf(wmax, __shfl_xor(wmax, 32));
        unsigned long long bal = __ballot(iou == wmax);
        if (lane == 0) {
            int wl = __ffsll(bal) - 1;            // lowest lane == smallest m
            unsigned wmm = (unsigned)(wm_base + wl);
            swave[wid][j] =
                ((unsigned long long)__float_as_uint(wmax) << 32) |
                (unsigned long long)(0xFFFFFFFFu - wmm);
        }
    }

    if (m < M) {
        unsigned n_global = (unsigned)(n0 + bestj);
        part1[(size_t)ns * MPAD + m] =
            ((unsigned long long)__float_as_uint(best) << 32) |
            (unsigned long long)(0xFFFFFFFFu - n_global);
        if (ns == 0) force_n[m] = -1;   // init for RS's atomicMax (replay-safe)
    }

    __syncthreads();
    if (tid < GT_CHUNK) {
        unsigned long long v = swave[0][tid];
        if (swave[1][tid] > v) v = swave[1][tid];
        if (swave[2][tid] > v) v = swave[2][tid];
        if (swave[3][tid] > v) v = swave[3][tid];
        atomicMax(&partG[n0 + tid], v);   // commutative -> deterministic
    }
}

// ---------------- RS: per-GT winner -> forced-assignment scatter -------------
__global__ void rs_kernel(const unsigned long long* __restrict__ partG,
                          int* __restrict__ force_n) {
    int n = blockIdx.x * blockDim.x + threadIdx.x;
    if (n >= N_GT) return;
    unsigned long long v = partG[n];
    int m = (int)(0xFFFFFFFFu - (unsigned)(v & 0xFFFFFFFFull));
    atomicMax(&force_n[m], n);   // duplicate priors: last write in np == max n
}

// ---------------- E: reduce per-prior partials + encode ----------------------
__global__ void __launch_bounds__(256) encode_kernel(
        const float* __restrict__ bboxes,
        const int* __restrict__ labels,
        const float* __restrict__ priors,
        const unsigned long long* __restrict__ part1,  // [NS][MPAD]
        const int* __restrict__ force_n,
        float* __restrict__ out, int M) {
#pragma clang fp contract(off)
    int m = blockIdx.x * 256 + threadIdx.x;
    if (m >= M) return;

    unsigned long long best = part1[m];
    for (int ns = 1; ns < NS; ++ns) {
        unsigned long long v = part1[(size_t)ns * MPAD + m];
        if (v > best) best = v;
    }
    float iou = __uint_as_float((unsigned)(best >> 32));
    int mid = (int)(0xFFFFFFFFu - (unsigned)(best & 0xFFFFFFFFull));

    int f = force_n[m];
    if (f >= 0) { mid = f; iou = POS_THRESH; }

    float4 g = reinterpret_cast<const float4*>(bboxes)[mid];
    float mcx = (g.x + g.z) / 2.0f;
    float mcy = (g.y + g.w) / 2.0f;
    float mw = g.z - g.x;
    float mh = g.w - g.y;

    float4 p = reinterpret_cast<const float4*>(priors)[m];
    float dcx = ((mcx - p.x) / p.z) / 0.1f;
    float dcy = ((mcy - p.y) / p.w) / 0.1f;
    float dw = logf(mw / p.z) / 0.2f;
    float dh = logf(mh / p.w) / 0.2f;

    reinterpret_cast<float4*>(out)[m] = make_float4(dcx, dcy, dw, dh);

    int cls = labels[mid];
    if (iou < POS_THRESH) cls = -1;
    if (iou < NEG_THRESH) cls = 0;
    out[(size_t)4 * M + m] = (float)cls;
}

extern "C" void kernel_launch(void* const* d_in, const int* in_sizes, int n_in,
                              void* d_out, int out_size, void* d_ws, size_t ws_size,
                              hipStream_t stream) {
    const float* bboxes = (const float*)d_in[0];
    const int* labels = (const int*)d_in[1];
    const float* priors = (const float*)d_in[2];
    int M = in_sizes[2] / 4;
    float* out = (float*)d_out;

    int mb = (M + 255) / 256;   // 192 prior blocks

    char* ws = (char*)d_ws;
    unsigned long long* part1 = (unsigned long long*)ws;                        // NS*MPAD u64 = 3.0 MB
    unsigned long long* partG = (unsigned long long*)(ws + (size_t)NS * MPAD * 8);  // N_GT u64
    int* force_n = (int*)(ws + (size_t)NS * MPAD * 8 + (size_t)N_GT * 8);       // M ints

    // partG must be 0 before fused_kernel's atomicMax (replay-safe)
    hipMemsetAsync(partG, 0, (size_t)N_GT * 8, stream);

    fused_kernel<<<dim3(mb, NS), 256, 0, stream>>>(bboxes, priors, part1, partG, force_n, M);
    rs_kernel<<<(N_GT + 255) / 256, 256, 0, stream>>>(partG, force_n);
    encode_kernel<<<mb, 256, 0, stream>>>(bboxes, labels, priors, part1, force_n, out, M);
}